// Round 3
// baseline (84.907 us; speedup 1.0000x reference)
//
#include <hip/hip_runtime.h>
#include <math.h>

#define EPS_F 1e-6f
#define CLIP_HI 0.999999f
#define IMG_W 224
#define IMG_H 224
#define ROWF (IMG_W * 3)   // 672 floats per (b,h) row

typedef float f32x4 __attribute__((ext_vector_type(4)));

__device__ __forceinline__ float clip01(float u) {
    return fminf(fmaxf(u, EPS_F), CLIP_HI);
}

// One-thread kernel: resolve the discrete decisions into 2 stage descriptors.
// dec layout (8 floats): [active0, a0, b0, m0, active1, a1, b1, m1]
// Stage backmap (when active): src_x = rint((float)w + (a*h + b)), valid iff 0<=src_x<W.
__global__ void decide_kernel(const float* __restrict__ spw,
                              const float* __restrict__ spp,
                              const float* __restrict__ spm,
                              const float* __restrict__ ug,
                              const float* __restrict__ ul,
                              float* __restrict__ dec) {
    if (threadIdx.x != 0 || blockIdx.x != 0) return;
    for (int i = 0; i < 2; ++i) {
        // gumbel-softmax hard -> argmax(logits + g)
        float g0 = -logf(-logf(clip01(ug[i * 2 + 0])));
        float g1 = -logf(-logf(clip01(ug[i * 2 + 1])));
        int j = (spw[i * 2 + 0] + g0 >= spw[i * 2 + 1] + g1) ? 0 : 1;
        // relaxed bernoulli hard -> rint(sigmoid(logit(p) + logit(u)))
        float p = clip01(spp[i * 2 + j]);
        float uc = clip01(ul[i * 2 + j]);
        float l = logf(uc) - log1pf(-uc);
        float s = (logf(p) - log1pf(-p)) + l;   // tau = 1
        float y = 1.0f / (1.0f + expf(-s));
        int hw = (int)rintf(y);                  // half-to-even like jnp.round
        float m = spm[i * 2 + j];
        float active = 0.f, a = 0.f, b = 0.f;
        if (hw == 1) {
            active = 1.f;
            if (j == 0) {            // shear_x: x_src = w + (0.6m-0.3)*h
                a = 0.6f * m - 0.3f;
                b = 0.f;
            } else {                 // translate_x: x_src = w - (20m-10)
                a = 0.f;
                b = -(20.0f * m - 10.0f);
            }
        }
        dec[i * 4 + 0] = active;
        dec[i * 4 + 1] = a;
        dec[i * 4 + 2] = b;
        dec[i * 4 + 3] = m;
    }
}

// One thread per 8 consecutive output floats (rows are 672 floats, 672%8==0,
// so the 8-float group never straddles a row). All 8 gather loads are
// unconditional with row-clamped addresses (always in-bounds), issued
// back-to-back for full memory-level parallelism; validity is applied
// afterwards with cndmask. Stores are two nontemporal float4 (write-only
// stream, keep it out of L2/L3 so the input stays cached).
__global__ __launch_bounds__(256) void warp_kernel(const float* __restrict__ x,
                                                   const float* __restrict__ dec,
                                                   float* __restrict__ out,
                                                   int total_q) {
    int q = blockIdx.x * 256 + threadIdx.x;
    if (q >= total_q) return;
    int pos = q * 8;                  // global float index
    int row = pos / ROWF;             // b*H + h
    int within = pos - row * ROWF;    // float offset within row
    int h = row % IMG_H;
    int base = row * ROWF;

    // wave-uniform decision scalars
    const float act0 = dec[0], a0 = dec[1], b0 = dec[2], m0 = dec[3];
    const float act1 = dec[4], a1 = dec[5], b1 = dec[6], m1 = dec[7];
    const bool s1on = (act1 != 0.f);
    const bool s0on = (act0 != 0.f);
    const float hf = (float)h;
    const float sh1 = a1 * hf + b1;   // row-uniform shift, stage applied second
    const float sh0 = a0 * hf + b0;   // row-uniform shift, stage applied first

    int w = within / 3;
    int c = within - w * 3;

    int srcs[8];
    bool vs[8];
#pragma unroll
    for (int e = 0; e < 8; ++e) {
        bool v = true;
        int w1 = w;
        if (s1on) {                    // back-map through stage 1 first
            int xi = (int)rintf((float)w + sh1);
            v = (xi >= 0) && (xi < IMG_W);
            w1 = xi;
        }
        int w0 = w1;
        if (s0on) {                    // then through stage 0
            int xi = (int)rintf((float)w1 + sh0);
            v = v && (xi >= 0) && (xi < IMG_W);
            w0 = xi;
        }
        int w0c = min(max(w0, 0), IMG_W - 1);   // always-in-bounds address
        srcs[e] = base + w0c * 3 + c;
        vs[e] = v;
        ++c; if (c == 3) { c = 0; ++w; }        // incremental (w, channel)
    }

    float vals[8];
#pragma unroll
    for (int e = 0; e < 8; ++e) vals[e] = x[srcs[e]];   // 8 loads in flight

    float r[8];
#pragma unroll
    for (int e = 0; e < 8; ++e) {
        float val = vs[e] ? vals[e] : 0.f;
        // per-stage value map (v+m0)-m0+m1)-m1 — fp-exact nudge; exact 0 stays 0
        r[e] = (((val + m0) - m0) + m1) - m1;
        r[e] = vs[e] ? r[e] : 0.f;
    }

    f32x4 o0 = { r[0], r[1], r[2], r[3] };
    f32x4 o1 = { r[4], r[5], r[6], r[7] };
    __builtin_nontemporal_store(o0, reinterpret_cast<f32x4*>(&out[pos]));
    __builtin_nontemporal_store(o1, reinterpret_cast<f32x4*>(&out[pos + 4]));
}

extern "C" void kernel_launch(void* const* d_in, const int* in_sizes, int n_in,
                              void* d_out, int out_size, void* d_ws, size_t ws_size,
                              hipStream_t stream) {
    const float* x   = (const float*)d_in[0];
    const float* spw = (const float*)d_in[1];
    const float* spp = (const float*)d_in[2];
    const float* spm = (const float*)d_in[3];
    const float* ug  = (const float*)d_in[4];
    const float* ul  = (const float*)d_in[5];
    float* dec = (float*)d_ws;
    float* out = (float*)d_out;

    decide_kernel<<<1, 1, 0, stream>>>(spw, spp, spm, ug, ul, dec);

    int total_q = out_size / 8;                 // rows (672) divisible by 8
    int blocks = (total_q + 255) / 256;
    warp_kernel<<<blocks, 256, 0, stream>>>(x, dec, out, total_q);
}

// Round 4
// 56.713 us; speedup vs baseline: 1.4971x; 1.4971x over previous
//
#include <hip/hip_runtime.h>
#include <math.h>

#define EPS_F 1e-6f
#define CLIP_HI 0.999999f
#define IMG_W 224
#define IMG_H 224
#define ROWF (IMG_W * 3)   // 672 floats per (b,h) row; 672 % 4 == 0

typedef float f32x4 __attribute__((ext_vector_type(4)));
typedef float f32x4_u __attribute__((ext_vector_type(4), aligned(4)));  // dword-aligned vector load

__device__ __forceinline__ float clip01(float u) {
    return fminf(fmaxf(u, EPS_F), CLIP_HI);
}

// One-thread kernel: resolve the discrete decisions into 2 stage descriptors.
// dec layout (8 floats): [active0, a0, b0, m0, active1, a1, b1, m1]
// Inactive stage gets a=b=0 so its back-map is exactly identity (rint(w+0)=w).
__global__ void decide_kernel(const float* __restrict__ spw,
                              const float* __restrict__ spp,
                              const float* __restrict__ spm,
                              const float* __restrict__ ug,
                              const float* __restrict__ ul,
                              float* __restrict__ dec) {
    if (threadIdx.x != 0 || blockIdx.x != 0) return;
    for (int i = 0; i < 2; ++i) {
        // gumbel-softmax hard -> argmax(logits + g)
        float g0 = -logf(-logf(clip01(ug[i * 2 + 0])));
        float g1 = -logf(-logf(clip01(ug[i * 2 + 1])));
        int j = (spw[i * 2 + 0] + g0 >= spw[i * 2 + 1] + g1) ? 0 : 1;
        // relaxed bernoulli hard -> rint(sigmoid(logit(p) + logit(u)))
        float p = clip01(spp[i * 2 + j]);
        float uc = clip01(ul[i * 2 + j]);
        float l = logf(uc) - log1pf(-uc);
        float s = (logf(p) - log1pf(-p)) + l;   // tau = 1
        float y = 1.0f / (1.0f + expf(-s));
        int hw = (int)rintf(y);
        float m = spm[i * 2 + j];
        float active = 0.f, a = 0.f, b = 0.f;
        if (hw == 1) {
            active = 1.f;
            if (j == 0) {            // shear_x: x_src = w + (0.6m-0.3)*h
                a = 0.6f * m - 0.3f;
            } else {                 // translate_x: x_src = w - (20m-10)
                b = -(20.0f * m - 10.0f);
            }
        }
        dec[i * 4 + 0] = active;
        dec[i * 4 + 1] = a;
        dec[i * 4 + 2] = b;
        dec[i * 4 + 3] = m;
    }
}

// One thread per aligned output float4 (rows are 672 floats, 672%4==0, so a
// float4 never straddles a row and touches exactly two pixel columns wA,wA+1).
// Exact per-element back-map (two rint chains). Wave-uniform fast path: when
// all 4 elements are valid and the source is contiguous, a single dword-aligned
// dwordx4 load replaces 4 strided scalar gathers (lanes stride 16B -> every
// fetched byte used). Border/tie waves take the exact clamped-scalar fallback.
__global__ __launch_bounds__(256) void warp_kernel(const float* __restrict__ x,
                                                   const float* __restrict__ dec,
                                                   float* __restrict__ out,
                                                   int total_q) {
    int q = blockIdx.x * 256 + threadIdx.x;
    if (q >= total_q) return;
    int pos = q * 4;                  // global float index, 16B aligned
    int row = pos / ROWF;             // b*H + h
    int within = pos - row * ROWF;
    int h = row % IMG_H;
    int base = row * ROWF;

    const float a0 = dec[1], b0 = dec[2], m0 = dec[3];
    const float a1 = dec[5], b1 = dec[6], m1 = dec[7];
    const float hf = (float)h;
    const float sh1 = a1 * hf + b1;   // stage applied second -> inverted first
    const float sh0 = a0 * hf + b0;   // stage applied first

    int wA = within / 3;
    int cA = within - wA * 3;

    // back-map chain for column wA
    int x1A = (int)rintf((float)wA + sh1);
    bool vA = (x1A >= 0) && (x1A < IMG_W);
    int x0A = (int)rintf((float)x1A + sh0);
    vA = vA && (x0A >= 0) && (x0A < IMG_W);

    // back-map chain for column wA+1 (always <= 223 since wA <= 222 here)
    int x1B = (int)rintf((float)(wA + 1) + sh1);
    bool vB = (x1B >= 0) && (x1B < IMG_W);
    int x0B = (int)rintf((float)x1B + sh0);
    vB = vB && (x0B >= 0) && (x0B < IMG_W);

    bool fast = vA && vB && (x0B == x0A + 1);

    float r[4];
    if (__all(fast)) {
        // all 4 source floats are x[base + 3*x0A + cA .. +3], contiguous
        const f32x4_u* src = reinterpret_cast<const f32x4_u*>(&x[base + 3 * x0A + cA]);
        f32x4_u v = *src;
#pragma unroll
        for (int e = 0; e < 4; ++e)
            r[e] = (((v[e] + m0) - m0) + m1) - m1;   // fp-exact value nudge
    } else {
        int srcs[4];
        bool vs[4];
#pragma unroll
        for (int e = 0; e < 4; ++e) {
            int ce = cA + e;
            bool useB = (ce >= 3);
            int w0 = useB ? x0B : x0A;
            bool v = useB ? vB : vA;
            int cc = useB ? (ce - 3) : ce;
            int w0c = min(max(w0, 0), IMG_W - 1);    // in-bounds address
            srcs[e] = base + 3 * w0c + cc;
            vs[e] = v;
        }
        float vals[4];
#pragma unroll
        for (int e = 0; e < 4; ++e) vals[e] = x[srcs[e]];
#pragma unroll
        for (int e = 0; e < 4; ++e) {
            float t = vs[e] ? vals[e] : 0.f;
            t = (((t + m0) - m0) + m1) - m1;
            r[e] = vs[e] ? t : 0.f;
        }
    }

    f32x4 o = { r[0], r[1], r[2], r[3] };
    __builtin_nontemporal_store(o, reinterpret_cast<f32x4*>(&out[pos]));
}

extern "C" void kernel_launch(void* const* d_in, const int* in_sizes, int n_in,
                              void* d_out, int out_size, void* d_ws, size_t ws_size,
                              hipStream_t stream) {
    const float* x   = (const float*)d_in[0];
    const float* spw = (const float*)d_in[1];
    const float* spp = (const float*)d_in[2];
    const float* spm = (const float*)d_in[3];
    const float* ug  = (const float*)d_in[4];
    const float* ul  = (const float*)d_in[5];
    float* dec = (float*)d_ws;
    float* out = (float*)d_out;

    decide_kernel<<<1, 1, 0, stream>>>(spw, spp, spm, ug, ul, dec);

    int total_q = out_size / 4;
    int blocks = (total_q + 255) / 256;
    warp_kernel<<<blocks, 256, 0, stream>>>(x, dec, out, total_q);
}

// Round 5
// 53.266 us; speedup vs baseline: 1.5940x; 1.0647x over previous
//
#include <hip/hip_runtime.h>
#include <math.h>

#define EPS_F 1e-6f
#define CLIP_HI 0.999999f
#define IMG_W 224
#define IMG_H 224
#define ROWF (IMG_W * 3)   // 672 floats per (b,h) row; 672 % 4 == 0

typedef float f32x4 __attribute__((ext_vector_type(4)));
typedef float f32x4_u __attribute__((ext_vector_type(4), aligned(4)));  // dword-aligned vector load

__device__ __forceinline__ float clip01(float u) {
    return fminf(fmaxf(u, EPS_F), CLIP_HI);
}

// Back-map + gather one aligned output float4 at global float index `pos`.
// Fast path: all 4 elements valid and source contiguous -> one dwordx4 load.
__device__ __forceinline__ f32x4 process4(const float* __restrict__ x, int pos,
                                          float sh0_a, float sh0_b,
                                          float sh1_a, float sh1_b,
                                          float m0, float m1) {
    int row = pos / ROWF;
    int within = pos - row * ROWF;
    int h = row % IMG_H;
    int base = row * ROWF;
    float hf = (float)h;
    float sh1 = sh1_a * hf + sh1_b;   // stage applied second -> inverted first
    float sh0 = sh0_a * hf + sh0_b;   // stage applied first

    int wA = within / 3;
    int cA = within - wA * 3;

    int x1A = (int)rintf((float)wA + sh1);
    bool vA = (x1A >= 0) && (x1A < IMG_W);
    int x0A = (int)rintf((float)x1A + sh0);
    vA = vA && (x0A >= 0) && (x0A < IMG_W);

    int x1B = (int)rintf((float)(wA + 1) + sh1);
    bool vB = (x1B >= 0) && (x1B < IMG_W);
    int x0B = (int)rintf((float)x1B + sh0);
    vB = vB && (x0B >= 0) && (x0B < IMG_W);

    bool fast = vA && vB && (x0B == x0A + 1);

    f32x4 o;
    if (__all(fast)) {
        const f32x4_u* src = reinterpret_cast<const f32x4_u*>(&x[base + 3 * x0A + cA]);
        f32x4_u v = *src;
#pragma unroll
        for (int e = 0; e < 4; ++e)
            o[e] = (((v[e] + m0) - m0) + m1) - m1;   // fp-exact value nudge
    } else {
        int srcs[4];
        bool vs[4];
#pragma unroll
        for (int e = 0; e < 4; ++e) {
            int ce = cA + e;
            bool useB = (ce >= 3);
            int w0 = useB ? x0B : x0A;
            bool v = useB ? vB : vA;
            int cc = useB ? (ce - 3) : ce;
            int w0c = min(max(w0, 0), IMG_W - 1);
            srcs[e] = base + 3 * w0c + cc;
            vs[e] = v;
        }
        float vals[4];
#pragma unroll
        for (int e = 0; e < 4; ++e) vals[e] = x[srcs[e]];
#pragma unroll
        for (int e = 0; e < 4; ++e) {
            float t = vs[e] ? vals[e] : 0.f;
            t = (((t + m0) - m0) + m1) - m1;
            o[e] = vs[e] ? t : 0.f;
        }
    }
    return o;
}

// Grid exactly covers out_size/8 threads; each thread writes two float4s half
// an image-set apart (halfN floats; halfN is a whole number of rows), so every
// load/store instruction keeps a perfect 16B lane stride while each thread has
// 2 loads + 2 stores in flight. Decision scalars are computed once per block
// by thread 0 (no separate serialized dispatch).
__global__ __launch_bounds__(256) void warp_kernel(const float* __restrict__ x,
                                                   const float* __restrict__ spw,
                                                   const float* __restrict__ spp,
                                                   const float* __restrict__ spm,
                                                   const float* __restrict__ ug,
                                                   const float* __restrict__ ul,
                                                   float* __restrict__ out,
                                                   int halfN) {
    __shared__ float sdec[8];   // [a0,b0,m0,_, a1,b1,m1,_] (a,b=0 when inactive)
    if (threadIdx.x == 0) {
#pragma unroll
        for (int i = 0; i < 2; ++i) {
            float g0 = -logf(-logf(clip01(ug[i * 2 + 0])));
            float g1 = -logf(-logf(clip01(ug[i * 2 + 1])));
            int j = (spw[i * 2 + 0] + g0 >= spw[i * 2 + 1] + g1) ? 0 : 1;
            float p = clip01(spp[i * 2 + j]);
            float uc = clip01(ul[i * 2 + j]);
            float l = logf(uc) - log1pf(-uc);
            float s = (logf(p) - log1pf(-p)) + l;   // tau = 1
            float y = 1.0f / (1.0f + expf(-s));
            int hw = (int)rintf(y);
            float m = spm[i * 2 + j];
            float a = 0.f, b = 0.f;
            if (hw == 1) {
                if (j == 0) a = 0.6f * m - 0.3f;          // shear_x
                else        b = -(20.0f * m - 10.0f);     // translate_x
            }
            sdec[i * 4 + 0] = a;
            sdec[i * 4 + 1] = b;
            sdec[i * 4 + 2] = m;
            sdec[i * 4 + 3] = 0.f;
        }
    }
    __syncthreads();
    const float a0 = sdec[0], b0 = sdec[1], m0 = sdec[2];
    const float a1 = sdec[4], b1 = sdec[5], m1 = sdec[6];

    int q = blockIdx.x * 256 + threadIdx.x;
    int pos0 = q * 4;
    int pos1 = pos0 + halfN;

    f32x4 o0 = process4(x, pos0, a0, b0, a1, b1, m0, m1);
    f32x4 o1 = process4(x, pos1, a0, b0, a1, b1, m0, m1);

    __builtin_nontemporal_store(o0, reinterpret_cast<f32x4*>(&out[pos0]));
    __builtin_nontemporal_store(o1, reinterpret_cast<f32x4*>(&out[pos1]));
}

extern "C" void kernel_launch(void* const* d_in, const int* in_sizes, int n_in,
                              void* d_out, int out_size, void* d_ws, size_t ws_size,
                              hipStream_t stream) {
    const float* x   = (const float*)d_in[0];
    const float* spw = (const float*)d_in[1];
    const float* spp = (const float*)d_in[2];
    const float* spm = (const float*)d_in[3];
    const float* ug  = (const float*)d_in[4];
    const float* ul  = (const float*)d_in[5];
    float* out = (float*)d_out;

    int halfN = out_size / 2;                   // whole number of rows (28672)
    int threads = out_size / 8;                 // 2 float4 per thread
    int blocks = threads / 256;                 // exact: 18816
    warp_kernel<<<blocks, 256, 0, stream>>>(x, spw, spp, spm, ug, ul, out, halfN);
}

// Round 6
// 51.903 us; speedup vs baseline: 1.6359x; 1.0263x over previous
//
#include <hip/hip_runtime.h>
#include <math.h>

#define EPS_F 1e-6f
#define CLIP_HI 0.999999f
#define IMG_W 224
#define IMG_H 224
#define ROWF (IMG_W * 3)   // 672 floats per (b,h) row; 672 % 4 == 0

typedef float f32x4 __attribute__((ext_vector_type(4)));
typedef float f32x4_u __attribute__((ext_vector_type(4), aligned(4)));  // dword-aligned vector load

__device__ __forceinline__ float clip01(float u) {
    return fminf(fmaxf(u, EPS_F), CLIP_HI);
}

// Each thread handles 4 output float4s spaced a quarter of the tensor apart.
// quarterN = out_size/4 = 14336 rows = 64 whole images, so all 4 positions
// share the same h and the same within-row offset -> ONE back-map chain
// serves 4 loads/stores. Decision scalars computed per-block by thread 0.
__global__ __launch_bounds__(256) void warp_kernel(const float* __restrict__ x,
                                                   const float* __restrict__ spw,
                                                   const float* __restrict__ spp,
                                                   const float* __restrict__ spm,
                                                   const float* __restrict__ ug,
                                                   const float* __restrict__ ul,
                                                   float* __restrict__ out,
                                                   int quarterN) {
    __shared__ float sdec[8];   // [a0,b0,m0,_, a1,b1,m1,_] (a,b = 0 when inactive)
    if (threadIdx.x == 0) {
#pragma unroll
        for (int i = 0; i < 2; ++i) {
            float g0 = -logf(-logf(clip01(ug[i * 2 + 0])));
            float g1 = -logf(-logf(clip01(ug[i * 2 + 1])));
            int j = (spw[i * 2 + 0] + g0 >= spw[i * 2 + 1] + g1) ? 0 : 1;
            float p = clip01(spp[i * 2 + j]);
            float uc = clip01(ul[i * 2 + j]);
            float l = logf(uc) - log1pf(-uc);
            float s = (logf(p) - log1pf(-p)) + l;   // tau = 1
            float y = 1.0f / (1.0f + expf(-s));
            int hw = (int)rintf(y);
            float m = spm[i * 2 + j];
            float a = 0.f, b = 0.f;
            if (hw == 1) {
                if (j == 0) a = 0.6f * m - 0.3f;          // shear_x
                else        b = -(20.0f * m - 10.0f);     // translate_x
            }
            sdec[i * 4 + 0] = a;
            sdec[i * 4 + 1] = b;
            sdec[i * 4 + 2] = m;
            sdec[i * 4 + 3] = 0.f;
        }
    }
    __syncthreads();
    const float a0 = sdec[0], b0 = sdec[1], m0 = sdec[2];
    const float a1 = sdec[4], b1 = sdec[5], m1 = sdec[6];

    int q = blockIdx.x * 256 + threadIdx.x;
    int pos = q * 4;                  // float index within the first quarter
    int row = pos / ROWF;
    int within = pos - row * ROWF;
    int h = row % IMG_H;
    int base = row * ROWF;
    const float hf = (float)h;
    const float sh1 = a1 * hf + b1;   // stage applied second -> inverted first
    const float sh0 = a0 * hf + b0;   // stage applied first

    int wA = within / 3;
    int cA = within - wA * 3;

    // shared back-map chain (identical for all 4 quarter-streams)
    int x1A = (int)rintf((float)wA + sh1);
    bool vA = (x1A >= 0) && (x1A < IMG_W);
    int x0A = (int)rintf((float)x1A + sh0);
    vA = vA && (x0A >= 0) && (x0A < IMG_W);

    int x1B = (int)rintf((float)(wA + 1) + sh1);
    bool vB = (x1B >= 0) && (x1B < IMG_W);
    int x0B = (int)rintf((float)x1B + sh0);
    vB = vB && (x0B >= 0) && (x0B < IMG_W);

    bool fast = vA && vB && (x0B == x0A + 1);

    f32x4 o[4];
    if (__all(fast)) {
        int srcoff = base + 3 * x0A + cA;       // contiguous 4-float source
#pragma unroll
        for (int k = 0; k < 4; ++k) {
            f32x4_u v = *reinterpret_cast<const f32x4_u*>(&x[srcoff + k * quarterN]);
#pragma unroll
            for (int e = 0; e < 4; ++e)
                o[k][e] = (((v[e] + m0) - m0) + m1) - m1;   // fp-exact nudge
        }
    } else {
        int offs[4];
        bool vs[4];
#pragma unroll
        for (int e = 0; e < 4; ++e) {
            int ce = cA + e;
            bool useB = (ce >= 3);
            int w0 = useB ? x0B : x0A;
            bool v = useB ? vB : vA;
            int cc = useB ? (ce - 3) : ce;
            int w0c = min(max(w0, 0), IMG_W - 1);
            offs[e] = base + 3 * w0c + cc;
            vs[e] = v;
        }
#pragma unroll
        for (int k = 0; k < 4; ++k) {
            float vals[4];
#pragma unroll
            for (int e = 0; e < 4; ++e) vals[e] = x[offs[e] + k * quarterN];
#pragma unroll
            for (int e = 0; e < 4; ++e) {
                float t = vs[e] ? vals[e] : 0.f;
                t = (((t + m0) - m0) + m1) - m1;
                o[k][e] = vs[e] ? t : 0.f;
            }
        }
    }

#pragma unroll
    for (int k = 0; k < 4; ++k)
        __builtin_nontemporal_store(o[k], reinterpret_cast<f32x4*>(&out[pos + k * quarterN]));
}

extern "C" void kernel_launch(void* const* d_in, const int* in_sizes, int n_in,
                              void* d_out, int out_size, void* d_ws, size_t ws_size,
                              hipStream_t stream) {
    const float* x   = (const float*)d_in[0];
    const float* spw = (const float*)d_in[1];
    const float* spp = (const float*)d_in[2];
    const float* spm = (const float*)d_in[3];
    const float* ug  = (const float*)d_in[4];
    const float* ul  = (const float*)d_in[5];
    float* out = (float*)d_out;

    int quarterN = out_size / 4;                // 14336 whole rows = 64 images
    int threads = quarterN / 4;                 // one float4 per stream
    int blocks = threads / 256;                 // exact: 9408
    warp_kernel<<<blocks, 256, 0, stream>>>(x, spw, spp, spm, ug, ul, out, quarterN);
}